// Round 7
// baseline (549.519 us; speedup 1.0000x reference)
//
#include <hip/hip_runtime.h>
#include <math.h>

#define NEGF -1000000000.0f
#define EPSF 1e-7f

// B=32, T=256, IN=64, H=128, 4H=512, TOP_K=5

// Pin a float4's components in VGPRs: volatile asm cannot be duplicated or
// sunk into the loop, so the loaded values must stay live across iterations
// (defeats MachineLICM/Sink rematerializing the invariant global loads,
// which re-streamed 256 KB/block/step of W_hh through L2 in rounds 2-6).
#define KEEP4(v) __asm__ volatile("" : "+v"((v).x), "+v"((v).y), "+v"((v).z), "+v"((v).w))

__device__ __forceinline__ float fsigmoid(float x) {
  return 1.0f / (1.0f + __expf(-x));               // overflow -> correct limit
}
__device__ __forceinline__ float ftanh(float x) {
  return 1.0f - 2.0f / (1.0f + __expf(2.0f * x));  // limits +-1: correct
}

// wave64 all-reduce sum via DPP (row_shr 1/2/4/8 + row_bcast 15/31), ~35 cyc.
__device__ __forceinline__ float wave_allsum(float v) {
#if __has_builtin(__builtin_amdgcn_update_dpp) && __has_builtin(__builtin_amdgcn_readlane)
  float f = v;
#define DPPSTEP(ctrl, rmask) { \
    int t = __builtin_amdgcn_update_dpp(0, __builtin_bit_cast(int, f), \
                                        ctrl, rmask, 0xf, true); \
    f += __builtin_bit_cast(float, t); }
  DPPSTEP(0x111, 0xf)   // row_shr:1
  DPPSTEP(0x112, 0xf)   // row_shr:2
  DPPSTEP(0x114, 0xf)   // row_shr:4
  DPPSTEP(0x118, 0xf)   // row_shr:8  -> lane15 of each row has row sum
  DPPSTEP(0x142, 0xa)   // row_bcast:15 into rows 1,3
  DPPSTEP(0x143, 0x8)   // row_bcast:31 into row 3 -> lane 63 = total
#undef DPPSTEP
  return __builtin_bit_cast(float,
      __builtin_amdgcn_readlane(__builtin_bit_cast(int, f), 63));
#else
  for (int off = 1; off < 64; off <<= 1) v += __shfl_xor(v, off, 64);
  return v;
#endif
}

// Kernel 1: xw[b][t][g] = x[b][t] . W_ih[g] + (b_ih[g]+b_hh[g])
// grid (T/8, B, 2): gates split 256/block; thread owns HALF a W_ih row
// (8 float4 = 32 VGPRs, asm-pinned) -> resident at any register budget.
__global__ __launch_bounds__(512) void xw_kernel(
    const float* __restrict__ x, const float* __restrict__ W_ih,
    const float* __restrict__ b_ih, const float* __restrict__ b_hh,
    float* __restrict__ xw)
{
  const int t0 = blockIdx.x * 8;
  const int b  = blockIdx.y;
  const int gl = threadIdx.x & 255;
  const int g  = (blockIdx.z << 8) + gl;
  const int hf = threadIdx.x >> 8;           // k-half 0/1

  __shared__ float sx[8][64];                // 2 KB
  __shared__ float sp[2][256];
  {
    int idx = threadIdx.x;                   // 512 = 8*64 exactly
    int tt = idx >> 6, k = idx & 63;
    sx[tt][k] = x[(size_t)(b * 256 + t0 + tt) * 64 + k];
  }
  const float4* wr = (const float4*)(W_ih + (size_t)g * 64 + (hf << 5));
  float4 w0 = wr[0], w1 = wr[1], w2 = wr[2], w3 = wr[3],
         w4 = wr[4], w5 = wr[5], w6 = wr[6], w7 = wr[7];
  KEEP4(w0); KEEP4(w1); KEEP4(w2); KEEP4(w3);
  KEEP4(w4); KEEP4(w5); KEEP4(w6); KEEP4(w7);
  const float bias = (hf == 0) ? (b_ih[g] + b_hh[g]) : 0.0f;
  __syncthreads();
  for (int tt = 0; tt < 8; ++tt) {
    const float4* sx4 = (const float4*)(&sx[tt][hf << 5]);
    float a0 = 0.0f, a1 = 0.0f, a2 = 0.0f, a3 = 0.0f;
#define XSTEP(q) { float4 hv = sx4[q]; \
    a0 = fmaf(w##q.x, hv.x, a0); a1 = fmaf(w##q.y, hv.y, a1); \
    a2 = fmaf(w##q.z, hv.z, a2); a3 = fmaf(w##q.w, hv.w, a3); }
    XSTEP(0) XSTEP(1) XSTEP(2) XSTEP(3) XSTEP(4) XSTEP(5) XSTEP(6) XSTEP(7)
#undef XSTEP
    sp[hf][gl] = (a0 + a1) + (a2 + a3);
    __syncthreads();
    if (hf == 0)
      xw[(size_t)(b * 256 + t0 + tt) * 512 + g] = sp[0][gl] + sp[1][gl] + bias;
    __syncthreads();
  }
}

// Kernel 2: full recurrence, one block per batch element, 1024 threads.
// Thread t: K-chunk q = t>>8 (32 of 128 h values), gates (t&255), (t&255)+256:
// 64 fp32 weights in 16 named float4s, asm-pinned (no sink/remat), within
// the 128-VGPR cap from amdgpu_waves_per_eu(4,4).
// Phases B-D on wave 0 only (2 h-elements/lane, DPP reductions, fixed-5
// gather): 2 barriers/step. fp32 everywhere.
__global__
__attribute__((amdgpu_flat_work_group_size(1024, 1024), amdgpu_waves_per_eu(4, 4)))
void lstm_attn(
    const float* __restrict__ xw, const float* __restrict__ W_hh,
    const float* __restrict__ w_t, float* __restrict__ out)
{
  const int b   = blockIdx.x;
  const int tid = threadIdx.x;
  const int l   = tid & 63;       // lane
  const int wid = tid >> 6;
  const int p   = tid & 255;      // gate-pair id
  const int q   = tid >> 8;       // K-chunk 0..3 (wave-uniform)
  const int gA  = p;
  const int gB  = p + 256;

  __shared__ float ho[257 * 128];     // fp32 h history (131584 B)
  __shared__ float sh_part[4 * 512];  // gate partials [q][gate] (8 KB)
  __shared__ float sh_h[128];
  __shared__ float sh_d[257];         // cached tanh(h_t).w_b scores
  __shared__ int   sh_nnz;
  __shared__ int   sh_cidx[8];
  __shared__ float sh_cw[8];

  // one-time weight load: 16 named float4 = 64 VGPRs, pinned
  const float4* pA = (const float4*)(W_hh + (size_t)gA * 128 + (q << 5));
  const float4* pB = (const float4*)(W_hh + (size_t)gB * 128 + (q << 5));
  float4 wA0 = pA[0], wA1 = pA[1], wA2 = pA[2], wA3 = pA[3],
         wA4 = pA[4], wA5 = pA[5], wA6 = pA[6], wA7 = pA[7];
  float4 wB0 = pB[0], wB1 = pB[1], wB2 = pB[2], wB3 = pB[3],
         wB4 = pB[4], wB5 = pB[5], wB6 = pB[6], wB7 = pB[7];
  KEEP4(wA0); KEEP4(wA1); KEEP4(wA2); KEEP4(wA3);
  KEEP4(wA4); KEEP4(wA5); KEEP4(wA6); KEEP4(wA7);
  KEEP4(wB0); KEEP4(wB1); KEEP4(wB2); KEEP4(wB3);
  KEEP4(wB4); KEEP4(wB5); KEEP4(wB6); KEEP4(wB7);

  // wave0 per-lane persistent state (h elements j0=2l, j1=2l+1)
  const int j0 = 2 * l, j1 = 2 * l + 1;
  float c0 = 0.0f, c1 = 0.0f;
  float wa0 = 0.0f, wa1 = 0.0f, wb0 = 0.0f, wb1 = 0.0f;
  float t5_0 = 0.0f, t5_1 = NEGF, t5_2 = NEGF, t5_3 = NEGF, t5_4 = NEGF;
  if (wid == 0) {
    wa0 = w_t[j0];       wa1 = w_t[j1];
    wb0 = w_t[128 + j0]; wb1 = w_t[128 + j1];
    sh_h[j0] = 0.0f; sh_h[j1] = 0.0f;   // h(-1) = 0
    ho[j0]   = 0.0f; ho[j1]   = 0.0f;   // history row 0
  }
  if (tid == 0) { sh_d[0] = 0.0f; sh_nnz = 0; }
  __syncthreads();

  const float* xwb = xw + (size_t)b * 256 * 512;
  float xcurA = 0.0f, xcurB = 0.0f;
  if (q == 0) { xcurA = xwb[gA]; xcurB = xwb[gB]; }

  for (int i = 0; i < 256; ++i) {
    const int rem = i + 1;

    // ---- Phase A: gate partials (64 FMAs from pinned-VGPR fp32 weights) ----
    float aA0 = xcurA, aA1 = 0.0f, aB0 = xcurB, aB1 = 0.0f;
    if (q == 0 && i < 255) {          // prefetch next step's xw
      xcurA = xwb[(size_t)(i + 1) * 512 + gA];
      xcurB = xwb[(size_t)(i + 1) * 512 + gB];
    }
    const float4* hh4 = (const float4*)(sh_h + (q << 5));
#define LSTEP(j) { float4 hv = hh4[j]; \
    aA0 = fmaf(wA##j.x, hv.x, aA0); aA1 = fmaf(wA##j.y, hv.y, aA1); \
    aA0 = fmaf(wA##j.z, hv.z, aA0); aA1 = fmaf(wA##j.w, hv.w, aA1); \
    aB0 = fmaf(wB##j.x, hv.x, aB0); aB1 = fmaf(wB##j.y, hv.y, aB1); \
    aB0 = fmaf(wB##j.z, hv.z, aB0); aB1 = fmaf(wB##j.w, hv.w, aB1); }
    LSTEP(0) LSTEP(1) LSTEP(2) LSTEP(3) LSTEP(4) LSTEP(5) LSTEP(6) LSTEP(7)
#undef LSTEP
    sh_part[(q << 9) + gA] = aA0 + aA1;
    sh_part[(q << 9) + gB] = aB0 + aB1;
    __syncthreads();                                      // S1

    if (wid == 0) {
      // ---- housekeeping + early loads (hide LDS latency) ----
      if (l < 8) { sh_cidx[l] = 0; sh_cw[l] = 0.0f; }     // pad gather slots
      if (l == 0) sh_nnz = 0;
      float d0 = sh_d[l], d1 = sh_d[l + 64],
            d2 = sh_d[l + 128], d3 = sh_d[l + 192];

      // ---- Phase B: LSTM cell (2 elements/lane) ----
#define GSUM(base) ({ \
      float2 x0 = ((const float2*)(sh_part        + (base)))[l]; \
      float2 x1 = ((const float2*)(sh_part +  512 + (base)))[l]; \
      float2 x2 = ((const float2*)(sh_part + 1024 + (base)))[l]; \
      float2 x3 = ((const float2*)(sh_part + 1536 + (base)))[l]; \
      float2 r; r.x = (x0.x + x1.x) + (x2.x + x3.x); \
      r.y = (x0.y + x1.y) + (x2.y + x3.y); r; })
      float2 Pi = GSUM(0), Pf = GSUM(128), Pg = GSUM(256), Po = GSUM(384);
#undef GSUM
      c0 = fsigmoid(Pf.x) * c0 + fsigmoid(Pi.x) * ftanh(Pg.x);
      c1 = fsigmoid(Pf.y) * c1 + fsigmoid(Pi.y) * ftanh(Pg.y);
      float hc0 = fsigmoid(Po.x) * ftanh(c0);
      float hc1 = fsigmoid(Po.y) * ftanh(c1);
      const float a = wave_allsum(ftanh(hc0) * wa0 + ftanh(hc1) * wa1);

      // ---- Phase C: scores at t = l, l+64, l+128, l+192 ----
      const float delta = (a + t5_4) + EPSF;
      float dv[4] = {d0, d1, d2, d3};
      float wv[4]; float wsum = 0.0f;
      #pragma unroll
      for (int m = 0; m < 4; ++m) {
        int t = l + 64 * m;
        float s = a + dv[m];
        float w = s - delta;
        w = (w > 0.0f) ? w : 0.0f;
        bool valid = (t < rem);
        wv[m] = valid ? w : 0.0f;
        wsum += wv[m];
        bool sel = valid && ((rem <= 5) || (w > 0.0f));
        if (sel) {
          int pp = atomicAdd(&sh_nnz, 1);
          float cv = (rem <= 5) ? s : w;
          if (pp < 8) { sh_cidx[pp] = t; sh_cw[pp] = cv; }
        }
      }
      wsum = wave_allsum(wsum);
      const float inv = (rem <= 5) ? 1.0f : 1.0f / (wsum + EPSF);
      if (i == 255) {
        #pragma unroll
        for (int m = 0; m < 4; ++m)
          out[4096 + b * 256 + (l + 64 * m)] = wv[m] * inv;  // final attn_w
      }

      // ---- Phase D: fixed-5 gather (nz<=5 provable; slots padded w=0) ----
      int   i0 = sh_cidx[0], i1 = sh_cidx[1], i2 = sh_cidx[2],
            i3 = sh_cidx[3], i4 = sh_cidx[4];
      float g0 = sh_cw[0], g1 = sh_cw[1], g2 = sh_cw[2],
            g3 = sh_cw[3], g4 = sh_cw[4];
      float at0 = g0 * ho[i0 * 128 + j0];
      float at1 = g0 * ho[i0 * 128 + j1];
      at0 = fmaf(g1, ho[i1 * 128 + j0], at0);
      at1 = fmaf(g1, ho[i1 * 128 + j1], at1);
      at0 = fmaf(g2, ho[i2 * 128 + j0], at0);
      at1 = fmaf(g2, ho[i2 * 128 + j1], at1);
      at0 = fmaf(g3, ho[i3 * 128 + j0], at0);
      at1 = fmaf(g3, ho[i3 * 128 + j1], at1);
      at0 = fmaf(g4, ho[i4 * 128 + j0], at0);
      at1 = fmaf(g4, ho[i4 * 128 + j1], at1);
      at0 *= inv; at1 *= inv;
      float hn0 = hc0 + at0, hn1 = hc1 + at1;
      sh_h[j0] = hn0; sh_h[j1] = hn1;
      ho[rem * 128 + j0] = hn0;
      ho[rem * 128 + j1] = hn1;
      if (i == 255) { out[b * 128 + j0] = at0; out[b * 128 + j1] = at1; }
      float dn = wave_allsum(ftanh(hn0) * wb0 + ftanh(hn1) * wb1);
      if (l == 0) sh_d[rem] = dn;
      // replicated top-5 insert (identical in every lane of wave 0)
      float v = dn;
      if (v > t5_0) { float t = t5_0; t5_0 = v; v = t; }
      if (v > t5_1) { float t = t5_1; t5_1 = v; v = t; }
      if (v > t5_2) { float t = t5_2; t5_2 = v; v = t; }
      if (v > t5_3) { float t = t5_3; t5_3 = v; v = t; }
      if (v > t5_4) { t5_4 = v; }
    }
    __syncthreads();                                      // S2
  }
}

extern "C" void kernel_launch(void* const* d_in, const int* in_sizes, int n_in,
                              void* d_out, int out_size, void* d_ws, size_t ws_size,
                              hipStream_t stream) {
  const float* x    = (const float*)d_in[0];  // (32,256,64)
  const float* W_ih = (const float*)d_in[1];  // (512,64)
  const float* W_hh = (const float*)d_in[2];  // (512,128)
  const float* b_ih = (const float*)d_in[3];  // (512,)
  const float* b_hh = (const float*)d_in[4];  // (512,)
  const float* w_t  = (const float*)d_in[5];  // (256,1)
  float* out = (float*)d_out;                 // [0:4096) attn_c, [4096:12288) attn_w

  float* xw = (float*)d_ws;                   // 32*256*512 fp32 = 16 MB

  xw_kernel<<<dim3(32, 32, 2), 512, 0, stream>>>(x, W_ih, b_ih, b_hh, xw);
  lstm_attn<<<dim3(32), 1024, 0, stream>>>(xw, W_hh, w_t, out);
}